// Round 1
// baseline (22284.309 us; speedup 1.0000x reference)
//
#include <hip/hip_runtime.h>
#include <math.h>

#define TT 512
#define NN 256
#define HH 512
constexpr float AL = 0.1f;

struct Args {
  const float* initdir; const float* vel; const float* fc_w; const float* fc_b;
  const float* W_in; const float* W_rec; const float* W_out; const float* bias;
  float* out; float* actbuf; unsigned* ctrs;
};

__global__ void init_ctrs(unsigned* ctrs) {
  ctrs[threadIdx.x + blockIdx.x * blockDim.x] = 0u;  // 4096 u32 = 16KB
}

// 256 WGs x 512 threads. Cluster = 4 WGs sharing a group of 4 batch rows.
// WG rank c owns columns [128c, 128c+128). W_rec slice in registers.
__global__ __launch_bounds__(512, 2)
void rnn_kernel(Args a) {
  __shared__ float4 act4[HH];       // act[i][n0..3], 8KB
  __shared__ float4 red4[16 * 64];  // partials [wave*2+jh][lane] -> 4 n, 16KB
  __shared__ float2 wout2[HH];      // W_out, 4KB

  const int tid = threadIdx.x;
  const int wav = tid >> 6;
  const int lan = tid & 63;
  const int bid = blockIdx.x;
  // cluster members share bid%8 -> same XCD under round-robin dispatch (heuristic only)
  const int xcd = bid & 7, k = bid >> 3;
  const int c = k & 3;                 // cluster rank 0..3
  const int grp = xcd * 8 + (k >> 2);  // n-group 0..63

  // update-phase identity: thread owns (un, uj)
  const int un = tid >> 7;             // n within group
  const int ujj = tid & 127;           // column within slice
  const int uj = c * 128 + ujj;        // global column
  const int ugn = grp * 4 + un;        // global batch row

  // GEMV identity: wave covers i in [64*wav, 64*wav+64), lane covers columns gj0, gj0+64
  const int gi0 = wav * 64;
  const int gj0 = c * 128 + lan;

  // ---- W_rec slice -> registers (one-time, 64MB total HBM traffic)
  float w0[64], w1[64];
  {
    const float* wr = a.W_rec + (size_t)gi0 * HH + gj0;
#pragma unroll
    for (int ii = 0; ii < 64; ++ii) {
      w0[ii] = wr[ii * HH];
      w1[ii] = wr[ii * HH + 64];
    }
  }
  wout2[tid] = ((const float2*)a.W_out)[tid];

  // per-thread parameters
  const float fw0 = a.fc_w[uj * 2], fw1 = a.fc_w[uj * 2 + 1], fb = a.fc_b[uj];
  const float wi0 = AL * a.W_in[uj], wi1 = AL * a.W_in[HH + uj];
  const float bj = AL * a.bias[uj];
  const float id0 = a.initdir[ugn * 2], id1 = a.initdir[ugn * 2 + 1];

  float h = fmaf(id0, fw0, fmaf(id1, fw1, fb));  // h0 = initdir @ fc_w^T + fc_b

  unsigned* ctr = a.ctrs + grp * 64;                       // 256B stride per cluster
  float* buf0 = a.actbuf + (size_t)grp * (HH * 4);         // parity 0
  float* buf1 = a.actbuf + (size_t)(64 + grp) * (HH * 4);  // parity 1

  // ---- initial exchange: act(h0) -> buf0
  {
    float act = fmaxf(tanhf(h), 0.0f);
    buf0[uj * 4 + un] = act;
  }
  __syncthreads();
  if (tid == 0) {
    __threadfence();
    __hip_atomic_fetch_add(ctr, 1u, __ATOMIC_RELEASE, __HIP_MEMORY_SCOPE_AGENT);
  }
  while (__hip_atomic_load(ctr, __ATOMIC_RELAXED, __HIP_MEMORY_SCOPE_AGENT) < 4u) {}
  __threadfence();
  act4[tid] = ((const float4*)buf0)[tid];
  __syncthreads();

  unsigned tgt = 8u;
  for (int t = 0; t < TT; ++t) {
    // velocities for this step (tiny broadcast load; hidden under GEMV)
    const float2 xv = ((const float2*)a.vel)[t * NN + ugn];

    // ---- phase A: GEMV partials over own i-chunk (weights from registers)
    float p00 = 0, p01 = 0, p10 = 0, p11 = 0, p20 = 0, p21 = 0, p30 = 0, p31 = 0;
#pragma unroll
    for (int ii = 0; ii < 64; ++ii) {
      float4 av = act4[gi0 + ii];  // broadcast read: act[i][n0..3]
      p00 = fmaf(av.x, w0[ii], p00); p01 = fmaf(av.x, w1[ii], p01);
      p10 = fmaf(av.y, w0[ii], p10); p11 = fmaf(av.y, w1[ii], p11);
      p20 = fmaf(av.z, w0[ii], p20); p21 = fmaf(av.z, w1[ii], p21);
      p30 = fmaf(av.w, w0[ii], p30); p31 = fmaf(av.w, w1[ii], p31);
    }
    red4[(wav * 2 + 0) * 64 + lan] = make_float4(p00, p10, p20, p30);
    red4[(wav * 2 + 1) * 64 + lan] = make_float4(p01, p11, p21, p31);
    __syncthreads();

    // ---- phase B: 8-way cross-wave reduce + state update (thread owns (un,uj))
    {
      const int jh = ujj >> 6, l2 = ujj & 63;
      const float* rp = (const float*)red4;
      float y = 0.f;
#pragma unroll
      for (int w = 0; w < 8; ++w) y += rp[((w * 2 + jh) * 64 + l2) * 4 + un];
      h = fmaf(0.9f, h, fmaf(AL, y, fmaf(xv.x, wi0, fmaf(xv.y, wi1, bj))));
    }
    float act = fmaxf(tanhf(h), 0.0f);

    float* bufw = (t & 1) ? buf0 : buf1;  // act_{t+1} -> parity (t+1)&1
    bufw[uj * 4 + un] = act;
    __syncthreads();  // red4 reads done; act stores drained (barrier implies vmcnt(0))
    if (tid == 0) {
      __threadfence();
      __hip_atomic_fetch_add(ctr, 1u, __ATOMIC_RELEASE, __HIP_MEMORY_SCOPE_AGENT);
    }
    while (__hip_atomic_load(ctr, __ATOMIC_RELAXED, __HIP_MEMORY_SCOPE_AGENT) < tgt) {}
    __threadfence();
    tgt += 4u;
    act4[tid] = ((const float4*)bufw)[tid];  // reload full act_{t+1} for group
    __syncthreads();

    // ---- out[t][grp*4+c][:] = act_{t+1}[n=c] @ W_out  (wave 0 of each WG)
    if (wav == 0) {
      float q0 = 0.f, q1 = 0.f;
#pragma unroll
      for (int kk = 0; kk < 8; ++kk) {
        int j = kk * 64 + lan;
        float av = ((const float*)&act4[j])[c];
        float2 wv = wout2[j];
        q0 = fmaf(av, wv.x, q0);
        q1 = fmaf(av, wv.y, q1);
      }
#pragma unroll
      for (int off = 32; off; off >>= 1) {
        q0 += __shfl_down(q0, off);
        q1 += __shfl_down(q1, off);
      }
      if (lan == 0) {
        float2* o = (float2*)a.out;
        o[t * NN + (grp * 4 + c)] = make_float2(q0, q1);
      }
    }
  }
}

extern "C" void kernel_launch(void* const* d_in, const int* in_sizes, int n_in,
                              void* d_out, int out_size, void* d_ws, size_t ws_size,
                              hipStream_t stream) {
  (void)in_sizes; (void)n_in; (void)out_size; (void)ws_size;
  Args a;
  a.initdir = (const float*)d_in[0];
  a.vel     = (const float*)d_in[1];
  a.fc_w    = (const float*)d_in[2];
  a.fc_b    = (const float*)d_in[3];
  a.W_in    = (const float*)d_in[4];
  a.W_rec   = (const float*)d_in[5];
  a.W_out   = (const float*)d_in[6];
  a.bias    = (const float*)d_in[7];
  a.out     = (float*)d_out;
  a.actbuf  = (float*)d_ws;                                   // 2 * 64 * 2048 f32 = 1MB
  a.ctrs    = (unsigned*)((char*)d_ws + 2 * 64 * 2048 * 4);   // +16KB counters

  init_ctrs<<<4, 1024, 0, stream>>>(a.ctrs);

  void* args[] = { &a };
  hipLaunchCooperativeKernel((const void*)rnn_kernel, dim3(256), dim3(512),
                             args, 0, stream);
}

// Round 2
// 1516.472 us; speedup vs baseline: 14.6948x; 14.6948x over previous
//
#include <hip/hip_runtime.h>
#include <math.h>

#define TT 512
#define NN 256
#define HH 512
constexpr float AL = 0.1f;

struct Args {
  const float* initdir; const float* vel; const float* fc_w; const float* fc_b;
  const float* W_in; const float* W_rec; const float* W_out; const float* bias;
  float* out; float* actbuf; unsigned* ctrs;
};

__global__ void init_ctrs(unsigned* ctrs) {
  ctrs[threadIdx.x + blockIdx.x * blockDim.x] = 0u;  // 4096 u32 = 16KB
}

__device__ __forceinline__ void st_agent(float* p, float v) {
  __hip_atomic_store(p, v, __ATOMIC_RELAXED, __HIP_MEMORY_SCOPE_AGENT);
}
__device__ __forceinline__ float ld_agent(const float* p) {
  return __hip_atomic_load(p, __ATOMIC_RELAXED, __HIP_MEMORY_SCOPE_AGENT);
}

// 256 WGs x 512 threads. Cluster = 4 WGs sharing a group of 4 batch rows.
// WG rank c owns columns [128c, 128c+128). W_rec slice lives in registers.
// Exchange: cache-bypassing (agent-scope) atomics through L3; relaxed counter
// handshake by thread 0 only -> no wbl2/inv cache maintenance anywhere.
__global__ __launch_bounds__(512, 2)
void rnn_kernel(Args a) {
  __shared__ float4 act4[HH];        // act[i][n0..3], 8KB
  __shared__ float red[16][4][64];   // [wav*2+jh][n][lane] partials, 16KB
  __shared__ float2 wout2[HH];       // W_out, 4KB

  const int tid = threadIdx.x;
  const int wav = tid >> 6;
  const int lan = tid & 63;
  const int bid = blockIdx.x;
  // cluster members share bid%8 -> same XCD under round-robin dispatch
  // (placement is a latency heuristic only; correctness is scope-based)
  const int xcd = bid & 7, k = bid >> 3;
  const int c = k & 3;                 // cluster rank 0..3
  const int grp = xcd * 8 + (k >> 2);  // n-group 0..63

  // update-phase identity: thread owns (un, uj)
  const int un = tid >> 7;             // n within group
  const int ujj = tid & 127;           // column within slice
  const int uj = c * 128 + ujj;        // global column
  const int ugn = grp * 4 + un;        // global batch row

  // GEMV identity: wave covers i in [64*wav, 64*wav+64), lane covers j = gj0, gj0+64
  const int gi0 = wav * 64;
  const int gj0 = c * 128 + lan;

  // ---- W_rec slice -> registers (one-time)
  float w0[64], w1[64];
  {
    const float* wr = a.W_rec + (size_t)gi0 * HH + gj0;
#pragma unroll
    for (int ii = 0; ii < 64; ++ii) {
      w0[ii] = wr[ii * HH];
      w1[ii] = wr[ii * HH + 64];
    }
  }
  wout2[tid] = ((const float2*)a.W_out)[tid];

  // per-thread parameters
  const float fw0 = a.fc_w[uj * 2], fw1 = a.fc_w[uj * 2 + 1], fb = a.fc_b[uj];
  const float wi0 = AL * a.W_in[uj], wi1 = AL * a.W_in[HH + uj];
  const float bj = AL * a.bias[uj];
  const float id0 = a.initdir[ugn * 2], id1 = a.initdir[ugn * 2 + 1];

  float h = fmaf(id0, fw0, fmaf(id1, fw1, fb));  // h0

  unsigned* ctr = a.ctrs + grp * 64;                       // 256B stride per cluster
  float* buf0 = a.actbuf + (size_t)grp * (HH * 4);         // parity 0: [n][512]
  float* buf1 = a.actbuf + (size_t)(64 + grp) * (HH * 4);  // parity 1

  // ---- initial exchange: act(h0) -> buf0
  st_agent(buf0 + un * HH + uj, fmaxf(tanhf(h), 0.0f));
  __syncthreads();  // implies vmcnt(0): stores complete at coherence point
  if (tid == 0) {
    __hip_atomic_fetch_add(ctr, 1u, __ATOMIC_RELAXED, __HIP_MEMORY_SCOPE_AGENT);
    while (__hip_atomic_load(ctr, __ATOMIC_RELAXED, __HIP_MEMORY_SCOPE_AGENT) < 4u)
      __builtin_amdgcn_s_sleep(1);
  }
  __syncthreads();
  {
    float t0 = ld_agent(buf0 + 0 * HH + tid), t1 = ld_agent(buf0 + 1 * HH + tid);
    float t2 = ld_agent(buf0 + 2 * HH + tid), t3 = ld_agent(buf0 + 3 * HH + tid);
    act4[tid] = make_float4(t0, t1, t2, t3);
  }
  __syncthreads();

  unsigned tgt = 8u;
  for (int t = 0; t < TT; ++t) {
    const float2 xv = ((const float2*)a.vel)[t * NN + ugn];

    // ---- phase A: GEMV partials over own i-chunk (weights in registers)
    float p00 = 0, p01 = 0, p10 = 0, p11 = 0, p20 = 0, p21 = 0, p30 = 0, p31 = 0;
#pragma unroll
    for (int ii = 0; ii < 64; ++ii) {
      float4 av = act4[gi0 + ii];  // broadcast LDS read (conflict-free)
      p00 = fmaf(av.x, w0[ii], p00); p01 = fmaf(av.x, w1[ii], p01);
      p10 = fmaf(av.y, w0[ii], p10); p11 = fmaf(av.y, w1[ii], p11);
      p20 = fmaf(av.z, w0[ii], p20); p21 = fmaf(av.z, w1[ii], p21);
      p30 = fmaf(av.w, w0[ii], p30); p31 = fmaf(av.w, w1[ii], p31);
    }
    // conflict-free b32 writes: lane index is fastest-varying
    red[wav * 2 + 0][0][lan] = p00; red[wav * 2 + 0][1][lan] = p10;
    red[wav * 2 + 0][2][lan] = p20; red[wav * 2 + 0][3][lan] = p30;
    red[wav * 2 + 1][0][lan] = p01; red[wav * 2 + 1][1][lan] = p11;
    red[wav * 2 + 1][2][lan] = p21; red[wav * 2 + 1][3][lan] = p31;
    __syncthreads();

    // ---- phase B: 8-way cross-wave reduce + state update
    {
      const int jh = ujj >> 6, l2 = ujj & 63;
      float y = 0.f;
#pragma unroll
      for (int w = 0; w < 8; ++w) y += red[w * 2 + jh][un][l2];  // conflict-free
      h = fmaf(0.9f, h, fmaf(AL, y, fmaf(xv.x, wi0, fmaf(xv.y, wi1, bj))));
    }
    float act = fmaxf(tanhf(h), 0.0f);

    float* bufw = (t & 1) ? buf0 : buf1;  // act_{t+1} -> parity (t+1)&1
    st_agent(bufw + un * HH + uj, act);   // coalesced, cache-bypassing
    __syncthreads();                      // vmcnt(0): stores globally visible
    if (tid == 0) {
      __hip_atomic_fetch_add(ctr, 1u, __ATOMIC_RELAXED, __HIP_MEMORY_SCOPE_AGENT);
      while (__hip_atomic_load(ctr, __ATOMIC_RELAXED, __HIP_MEMORY_SCOPE_AGENT) < tgt)
        __builtin_amdgcn_s_sleep(1);
    }
    __syncthreads();
    tgt += 4u;
    {
      float t0 = ld_agent(bufw + 0 * HH + tid), t1 = ld_agent(bufw + 1 * HH + tid);
      float t2 = ld_agent(bufw + 2 * HH + tid), t3 = ld_agent(bufw + 3 * HH + tid);
      act4[tid] = make_float4(t0, t1, t2, t3);
    }
    __syncthreads();

    // ---- out[t][grp*4+c][:] = act_{t+1}[n=c] @ W_out  (wave 0 only)
    if (wav == 0) {
      float q0 = 0.f, q1 = 0.f;
#pragma unroll
      for (int kk = 0; kk < 8; ++kk) {
        int j = kk * 64 + lan;
        float av = ((const float*)&act4[j])[c];
        float2 wv = wout2[j];
        q0 = fmaf(av, wv.x, q0);
        q1 = fmaf(av, wv.y, q1);
      }
#pragma unroll
      for (int off = 32; off; off >>= 1) {
        q0 += __shfl_down(q0, off);
        q1 += __shfl_down(q1, off);
      }
      if (lan == 0) {
        float2* o = (float2*)a.out;
        o[t * NN + (grp * 4 + c)] = make_float2(q0, q1);
      }
    }
  }
}

extern "C" void kernel_launch(void* const* d_in, const int* in_sizes, int n_in,
                              void* d_out, int out_size, void* d_ws, size_t ws_size,
                              hipStream_t stream) {
  (void)in_sizes; (void)n_in; (void)out_size; (void)ws_size;
  Args a;
  a.initdir = (const float*)d_in[0];
  a.vel     = (const float*)d_in[1];
  a.fc_w    = (const float*)d_in[2];
  a.fc_b    = (const float*)d_in[3];
  a.W_in    = (const float*)d_in[4];
  a.W_rec   = (const float*)d_in[5];
  a.W_out   = (const float*)d_in[6];
  a.bias    = (const float*)d_in[7];
  a.out     = (float*)d_out;
  a.actbuf  = (float*)d_ws;                                   // 2 * 64 * 2048 f32 = 1MB
  a.ctrs    = (unsigned*)((char*)d_ws + 2 * 64 * 2048 * 4);   // +16KB counters

  init_ctrs<<<4, 1024, 0, stream>>>(a.ctrs);

  void* args[] = { &a };
  hipLaunchCooperativeKernel((const void*)rnn_kernel, dim3(256), dim3(512),
                             args, 0, stream);
}

// Round 3
// 1426.277 us; speedup vs baseline: 15.6241x; 1.0632x over previous
//
#include <hip/hip_runtime.h>
#include <math.h>

#define TT 512
#define NN 256
#define HH 512
constexpr float AL = 0.1f;

typedef float f32x16 __attribute__((ext_vector_type(16)));

struct Args {
  const float* initdir; const float* vel; const float* fc_w; const float* fc_b;
  const float* W_in; const float* W_rec; const float* W_out; const float* bias;
  float* out; float* actbuf; unsigned* ctrs;
};

__global__ void init_ctrs(unsigned* ctrs) {
  ctrs[threadIdx.x + blockIdx.x * blockDim.x] = 0u;  // 4096 u32 = 16KB
}

__device__ __forceinline__ void st_agent(float* p, float v) {
  __hip_atomic_store(p, v, __ATOMIC_RELAXED, __HIP_MEMORY_SCOPE_AGENT);
}
__device__ __forceinline__ float ld_agent(const float* p) {
  return __hip_atomic_load(p, __ATOMIC_RELAXED, __HIP_MEMORY_SCOPE_AGENT);
}

// 256 WGs x 512 threads. Cluster = 4 WGs sharing a group of 4 batch rows.
// WG rank c owns columns [128c, 128c+128). W_rec slice lives in registers
// (forced via ext_vector SSA values -- plain float[64] arrays were demoted,
// VGPR_Count=84, costing ~2x VALU ops per FMA).
__global__ __launch_bounds__(512, 2)
void rnn_kernel(Args a) {
  __shared__ float4 act4[HH];        // act[i][n0..3], 8KB
  __shared__ float red[16][4][64];   // [wav*2+jh][n][lane] partials, 16KB
  __shared__ float2 wout2[HH];       // W_out, 4KB

  const int tid = threadIdx.x;
  const int wav = tid >> 6;
  const int lan = tid & 63;
  const int bid = blockIdx.x;
  // cluster members share bid%8 -> same XCD under round-robin dispatch
  const int xcd = bid & 7, k = bid >> 3;
  const int c = k & 3;                 // cluster rank 0..3
  const int grp = xcd * 8 + (k >> 2);  // n-group 0..63

  // update-phase identity: thread owns (un, uj)
  const int un = tid >> 7;             // n within group
  const int ujj = tid & 127;           // column within slice
  const int uj = c * 128 + ujj;        // global column
  const int ugn = grp * 4 + un;        // global batch row

  // GEMV identity: wave covers i in [64*wav, 64*wav+64), lane covers j = gj0, gj0+64
  const int gi0 = wav * 64;
  const int gj0 = c * 128 + lan;

  // ---- W_rec slice -> registers as SSA vector values (128 VGPRs)
  f32x16 w0[4], w1[4];  // constant-indexed only => SROA-promoted
  {
    const float* wr = a.W_rec + (size_t)gi0 * HH + gj0;
#pragma unroll
    for (int ii = 0; ii < 64; ++ii) {
      w0[ii >> 4][ii & 15] = wr[ii * HH];
      w1[ii >> 4][ii & 15] = wr[ii * HH + 64];
    }
  }
  wout2[tid] = ((const float2*)a.W_out)[tid];

  // per-thread parameters
  const float fw0 = a.fc_w[uj * 2], fw1 = a.fc_w[uj * 2 + 1], fb = a.fc_b[uj];
  const float wi0 = AL * a.W_in[uj], wi1 = AL * a.W_in[HH + uj];
  const float bj = AL * a.bias[uj];
  const float id0 = a.initdir[ugn * 2], id1 = a.initdir[ugn * 2 + 1];

  float h = fmaf(id0, fw0, fmaf(id1, fw1, fb));  // h0

  unsigned* ctr = a.ctrs + grp * 64;                       // 256B stride per cluster
  float* buf0 = a.actbuf + (size_t)grp * (HH * 4);         // parity 0: [n][512]
  float* buf1 = a.actbuf + (size_t)(64 + grp) * (HH * 4);  // parity 1

  // ---- initial exchange: act(h0) -> buf0
  st_agent(buf0 + un * HH + uj, fmaxf(tanhf(h), 0.0f));
  __syncthreads();  // implies vmcnt(0): stores complete at coherence point
  if (tid == 0) {
    __hip_atomic_fetch_add(ctr, 1u, __ATOMIC_RELAXED, __HIP_MEMORY_SCOPE_AGENT);
    while (__hip_atomic_load(ctr, __ATOMIC_RELAXED, __HIP_MEMORY_SCOPE_AGENT) < 4u)
      __builtin_amdgcn_s_sleep(1);
  }
  __syncthreads();
  {
    float t0 = ld_agent(buf0 + 0 * HH + tid), t1 = ld_agent(buf0 + 1 * HH + tid);
    float t2 = ld_agent(buf0 + 2 * HH + tid), t3 = ld_agent(buf0 + 3 * HH + tid);
    act4[tid] = make_float4(t0, t1, t2, t3);
  }
  __syncthreads();

  unsigned tgt = 8u;
  for (int t = 0; t < TT; ++t) {
    const float2 xv = ((const float2*)a.vel)[t * NN + ugn];

    // ---- phase A: GEMV partials over own i-chunk (weights in registers)
    float p00 = 0, p01 = 0, p10 = 0, p11 = 0, p20 = 0, p21 = 0, p30 = 0, p31 = 0;
#pragma unroll
    for (int ii = 0; ii < 64; ++ii) {
      float4 av = act4[gi0 + ii];  // broadcast LDS read (conflict-free)
      const float wa = w0[ii >> 4][ii & 15];
      const float wb = w1[ii >> 4][ii & 15];
      p00 = fmaf(av.x, wa, p00); p01 = fmaf(av.x, wb, p01);
      p10 = fmaf(av.y, wa, p10); p11 = fmaf(av.y, wb, p11);
      p20 = fmaf(av.z, wa, p20); p21 = fmaf(av.z, wb, p21);
      p30 = fmaf(av.w, wa, p30); p31 = fmaf(av.w, wb, p31);
    }
    // conflict-free b32 writes: lane index is fastest-varying
    red[wav * 2 + 0][0][lan] = p00; red[wav * 2 + 0][1][lan] = p10;
    red[wav * 2 + 0][2][lan] = p20; red[wav * 2 + 0][3][lan] = p30;
    red[wav * 2 + 1][0][lan] = p01; red[wav * 2 + 1][1][lan] = p11;
    red[wav * 2 + 1][2][lan] = p21; red[wav * 2 + 1][3][lan] = p31;
    __syncthreads();

    // ---- phase B: 8-way cross-wave reduce + state update
    {
      const int jh = ujj >> 6, l2 = ujj & 63;
      float y = 0.f;
#pragma unroll
      for (int w = 0; w < 8; ++w) y += red[w * 2 + jh][un][l2];  // conflict-free
      h = fmaf(0.9f, h, fmaf(AL, y, fmaf(xv.x, wi0, fmaf(xv.y, wi1, bj))));
    }
    float act = fmaxf(tanhf(h), 0.0f);

    float* bufw = (t & 1) ? buf0 : buf1;  // act_{t+1} -> parity (t+1)&1
    st_agent(bufw + un * HH + uj, act);   // coalesced, cache-bypassing
    __syncthreads();                      // vmcnt(0): stores globally visible
    if (tid == 0) {
      __hip_atomic_fetch_add(ctr, 1u, __ATOMIC_RELAXED, __HIP_MEMORY_SCOPE_AGENT);
      while (__hip_atomic_load(ctr, __ATOMIC_RELAXED, __HIP_MEMORY_SCOPE_AGENT) < tgt)
        __builtin_amdgcn_s_sleep(1);
    }
    __syncthreads();
    tgt += 4u;
    {
      float t0 = ld_agent(bufw + 0 * HH + tid), t1 = ld_agent(bufw + 1 * HH + tid);
      float t2 = ld_agent(bufw + 2 * HH + tid), t3 = ld_agent(bufw + 3 * HH + tid);
      act4[tid] = make_float4(t0, t1, t2, t3);
    }
    __syncthreads();

    // ---- out[t][grp*4+c][:] = act_{t+1}[n=c] @ W_out  (wave 0 only)
    if (wav == 0) {
      float q0 = 0.f, q1 = 0.f;
#pragma unroll
      for (int kk = 0; kk < 8; ++kk) {
        int j = kk * 64 + lan;
        float av = ((const float*)&act4[j])[c];
        float2 wv = wout2[j];
        q0 = fmaf(av, wv.x, q0);
        q1 = fmaf(av, wv.y, q1);
      }
#pragma unroll
      for (int off = 32; off; off >>= 1) {
        q0 += __shfl_down(q0, off);
        q1 += __shfl_down(q1, off);
      }
      if (lan == 0) {
        float2* o = (float2*)a.out;
        o[t * NN + (grp * 4 + c)] = make_float2(q0, q1);
      }
    }
  }
}

extern "C" void kernel_launch(void* const* d_in, const int* in_sizes, int n_in,
                              void* d_out, int out_size, void* d_ws, size_t ws_size,
                              hipStream_t stream) {
  (void)in_sizes; (void)n_in; (void)out_size; (void)ws_size;
  Args a;
  a.initdir = (const float*)d_in[0];
  a.vel     = (const float*)d_in[1];
  a.fc_w    = (const float*)d_in[2];
  a.fc_b    = (const float*)d_in[3];
  a.W_in    = (const float*)d_in[4];
  a.W_rec   = (const float*)d_in[5];
  a.W_out   = (const float*)d_in[6];
  a.bias    = (const float*)d_in[7];
  a.out     = (float*)d_out;
  a.actbuf  = (float*)d_ws;                                   // 2 * 64 * 2048 f32 = 1MB
  a.ctrs    = (unsigned*)((char*)d_ws + 2 * 64 * 2048 * 4);   // +16KB counters

  init_ctrs<<<4, 1024, 0, stream>>>(a.ctrs);

  void* args[] = { &a };
  hipLaunchCooperativeKernel((const void*)rnn_kernel, dim3(256), dim3(512),
                             args, 0, stream);
}